// Round 11
// baseline (492.596 us; speedup 1.0000x reference)
//
#include <hip/hip_runtime.h>
#include <hip/hip_bf16.h>
#include <cstdint>

typedef unsigned short ushortT;
typedef __attribute__((ext_vector_type(8))) short short8;
typedef __attribute__((ext_vector_type(4))) float f32x4;
typedef __attribute__((ext_vector_type(4))) unsigned short us4;

__device__ __forceinline__ ushortT f2bf(float f) {
  union { float f; unsigned u; } v; v.f = f;
  unsigned r = (v.u + 0x7FFFu + ((v.u >> 16) & 1u)) >> 16;
  return (ushortT)r;
}

__device__ __forceinline__ unsigned cvtpk(float lo, float hi) {
  unsigned r;
  asm("v_cvt_pk_bf16_f32 %0, %1, %2" : "=v"(r) : "v"(lo), "v"(hi));
  return r;
}

__device__ __forceinline__ void gl_lds16(const void* g, void* l) {
  __builtin_amdgcn_global_load_lds(
      (__attribute__((address_space(1))) void*)g,
      (__attribute__((address_space(3))) void*)l, 16, 0, 0);
}

// ===== fused f32->bf16 GEMM: y = x(f32) @ fused(bf16)^T + bias ==============
// r7 geometry: 256x128 tile, 8 waves (64x64/wave), mod-3 LDS (72 KiB),
// 2 blocks/CU, one barrier per K-step, counted vmcnt. A is reg-staged from
// f32 x (v_cvt_pk_bf16_f32 -> 2 ds_write_b128), killing the separate cvt pass.
// Ledger (per iter kt): issue A(kt+2) 4 loads -> vmcnt(4) retires
// A(kt+1)+B(kt+1) -> ds_write A(kt+1) -> lgkmcnt(0) -> barrier ->
// issue B(kt+2) gl_lds -> ds_read + 16 MFMA from buf kt%3.
// Buffers mod 3: writes hit (kt+1)%3 / B-DMA (kt+2)%3; readers on kt%3 ->
// disjoint in every barrier window. K=1024 hardcoded (NK=32).
__global__ __launch_bounds__(512, 4) void gemmfx(
    const float* __restrict__ X, const ushortT* __restrict__ B,
    float* __restrict__ outF, const float* __restrict__ bias)
{
  constexpr int NK = 32;
  constexpr int N = 2048;
  __shared__ ushortT smem[3 * 256 * 32 + 3 * 128 * 32];  // 72 KiB
  ushortT(*sA)[256 * 32] = (ushortT(*)[256 * 32])smem;
  ushortT(*sB)[128 * 32] = (ushortT(*)[128 * 32])(smem + 3 * 256 * 32);

  const int tid = threadIdx.x;
  const int wv = tid >> 6, l = tid & 63;
  const int wm = wv >> 1, wn = wv & 1;  // 4M x 2N waves, 64x64 each

  // XCD swizzle: n fast, m slow (per-XCD ws ~L2-resident, r8-verified)
  const int bid = blockIdx.x;
  const int xcd = bid & 7, ii = bid >> 3;
  const int n0 = (ii & 15) * 128;
  const int m0 = (xcd * 16 + (ii >> 4)) * 256;

  f32x4 acc[4][4] = {};

  // ---- A reg staging geometry: thread -> row ar, k-half ak (16 floats) ----
  const int ar = tid >> 1;
  const int ak = (tid & 1) * 16;
  const int aswz = (ar >> 1) & 3;
  const int ga0 = (tid & 1) * 2, ga1 = ga0 + 1;
  const float* Xrow = X + (size_t)(m0 + ar) * 1024 + ak;

  // ---- B staging (bf16 source, global_load_lds, r7 pattern) ----
  const ushortT* Bb = B + (size_t)n0 * 1024;
  const int rb = tid >> 2;
  const int gsb = (tid & 3) ^ ((rb >> 1) & 3);
  auto stageB = [&](int kt) {
    gl_lds16(Bb + (size_t)rb * 1024 + (size_t)((kt << 5) + (gsb << 3)),
             &sB[kt % 3][(wv * 16) * 32]);
  };

  auto writeA = [&](int kt, f32x4 (&wr)[4]) {
    ushortT* dst = &sA[kt % 3][ar * 32];
    union { unsigned u[4]; short8 s; } p0, p1;
    p0.u[0] = cvtpk(wr[0][0], wr[0][1]); p0.u[1] = cvtpk(wr[0][2], wr[0][3]);
    p0.u[2] = cvtpk(wr[1][0], wr[1][1]); p0.u[3] = cvtpk(wr[1][2], wr[1][3]);
    p1.u[0] = cvtpk(wr[2][0], wr[2][1]); p1.u[1] = cvtpk(wr[2][2], wr[2][3]);
    p1.u[2] = cvtpk(wr[3][0], wr[3][1]); p1.u[3] = cvtpk(wr[3][2], wr[3][3]);
    *(short8*)&dst[(ga0 ^ aswz) << 3] = p0.s;
    *(short8*)&dst[(ga1 ^ aswz) << 3] = p1.s;
  };

  const int fr = l & 15;
  const int colsw = (((l >> 4) ^ ((fr >> 1) & 3)) << 3);

  f32x4 ra0[4], ra1[4];

  // ---- prologue: A0->ra0, B0, A1->ra1, B1; retire A0+B0; write A0 ----
#pragma unroll
  for (int j = 0; j < 4; ++j) ra0[j] = *(const f32x4*)(Xrow + j * 4);
  stageB(0);
#pragma unroll
  for (int j = 0; j < 4; ++j) ra1[j] = *(const f32x4*)(Xrow + 32 + j * 4);
  stageB(1);
  asm volatile("s_waitcnt vmcnt(5)" ::: "memory");
  writeA(0, ra0);

  auto body = [&](int kt, f32x4 (&wr)[4], f32x4 (&ld)[4]) {
    if (kt + 2 < NK) {
#pragma unroll
      for (int j = 0; j < 4; ++j)
        ld[j] = *(const f32x4*)(Xrow + (kt + 2) * 32 + j * 4);
      asm volatile("s_waitcnt vmcnt(4)" ::: "memory");
    } else {
      asm volatile("s_waitcnt vmcnt(0)" ::: "memory");
    }
    if (kt + 1 < NK) writeA(kt + 1, wr);
    asm volatile("s_waitcnt lgkmcnt(0)" ::: "memory");
    __builtin_amdgcn_s_barrier();
    if (kt + 2 < NK) stageB(kt + 2);

    const ushortT* cA = sA[kt % 3];
    const ushortT* cB = sB[kt % 3];
    short8 av[4], bv[4];
#pragma unroll
    for (int f = 0; f < 4; ++f) {
      av[f] = *(const short8*)&cA[(wm * 64 + f * 16 + fr) * 32 + colsw];
      bv[f] = *(const short8*)&cB[(wn * 64 + f * 16 + fr) * 32 + colsw];
    }
    __builtin_amdgcn_s_setprio(1);
#pragma unroll
    for (int fi = 0; fi < 4; ++fi)
#pragma unroll
      for (int fj = 0; fj < 4; ++fj)
        acc[fi][fj] = __builtin_amdgcn_mfma_f32_16x16x32_bf16(
            av[fi], bv[fj], acc[fi][fj], 0, 0, 0);
    __builtin_amdgcn_s_setprio(0);
  };

#pragma unroll 1
  for (int kt2 = 0; kt2 < NK; kt2 += 2) {
    body(kt2, ra1, ra0);
    body(kt2 + 1, ra0, ra1);
  }

  // ---- epilogue: LDS transpose (padded) -> contiguous nt f32x4 stores ----
  const int cc = l & 15, r4 = (l >> 4) * 4;
  float bvv[4];
#pragma unroll
  for (int fj = 0; fj < 4; ++fj) bvv[fj] = bias[n0 + wn * 64 + fj * 16 + cc];

  float* lbuf = (float*)smem;  // 128 x 132 f32 = 67.6 KiB
#pragma unroll
  for (int s = 0; s < 2; ++s) {
    __syncthreads();
    if ((wm >> 1) == s) {
#pragma unroll
      for (int fi = 0; fi < 4; ++fi)
#pragma unroll
        for (int r = 0; r < 4; ++r) {
          const int row = (wm & 1) * 64 + fi * 16 + r4 + r;
#pragma unroll
          for (int fj = 0; fj < 4; ++fj)
            lbuf[row * 132 + wn * 64 + fj * 16 + cc] = acc[fi][fj][r] + bvv[fj];
        }
    }
    __syncthreads();
#pragma unroll
    for (int k = 0; k < 8; ++k) {
      const int f = k * 512 + tid;
      const int row = f >> 5, c4 = f & 31;
      f32x4 v = *(const f32x4*)&lbuf[row * 132 + c4 * 4];
      __builtin_nontemporal_store(
          v, (f32x4*)&outF[(size_t)(m0 + s * 128 + row) * (size_t)N + n0 + c4 * 4]);
    }
  }
}

// ---------------- 128x128 tile GEMM, C = A @ B^T, bf16 in, BK=32 -------------
template <int EPI>
__global__ __launch_bounds__(256) void gemm128(
    const ushortT* __restrict__ A, const ushortT* __restrict__ B,
    int M, int N, int K,
    float* __restrict__ outF, ushortT* __restrict__ outBF,
    const float* __restrict__ bias,
    const float* __restrict__ addend,
    float* __restrict__ S2, float* __restrict__ S4,
    ushortT* __restrict__ sdT, int ldT)
{
  __shared__ ushortT sA[2][128 * 32];
  __shared__ ushortT sB[2][128 * 32];
  const int tid = threadIdx.x;
  const int w = tid >> 6, l = tid & 63;
  const int wr = w >> 1, wc = w & 1;
  const int m0 = blockIdx.x * 128, n0 = blockIdx.y * 128;
  const int NK = K >> 5;

  f32x4 acc[4][4] = {};

  auto stage = [&](int buf, int kt) {
    const int k0 = kt << 5;
    const size_t colA = (size_t)(k0 + (l & 3) * 8);
    const int rb = w * 16 + (l >> 2);
#pragma unroll
    for (int c = 0; c < 2; ++c) {
      gl_lds16(A + (size_t)(m0 + c * 64 + rb) * (size_t)K + colA,
               &sA[buf][c * 2048 + w * 512]);
      gl_lds16(B + (size_t)(n0 + c * 64 + rb) * (size_t)K + colA,
               &sB[buf][c * 2048 + w * 512]);
    }
  };

  stage(0, 0);
  __syncthreads();

  for (int kt = 0; kt < NK; ++kt) {
    const int buf = kt & 1;
    if (kt + 1 < NK) stage(buf ^ 1, kt + 1);
    const int ro = (l & 15) * 32 + (l >> 4) * 8;
    short8 a[4], b[4];
#pragma unroll
    for (int f = 0; f < 4; ++f) {
      a[f] = *(const short8*)&sA[buf][(wr * 64 + f * 16) * 32 + ro];
      b[f] = *(const short8*)&sB[buf][(wc * 64 + f * 16) * 32 + ro];
    }
#pragma unroll
    for (int fi = 0; fi < 4; ++fi)
#pragma unroll
      for (int fj = 0; fj < 4; ++fj)
        acc[fi][fj] = __builtin_amdgcn_mfma_f32_16x16x32_bf16(
            a[fi], b[fj], acc[fi][fj], 0, 0, 0);
    __syncthreads();
  }

  const int r4 = (l >> 4) * 4, cc = l & 15;

  if constexpr (EPI == 1) {
#pragma unroll
    for (int fi = 0; fi < 4; ++fi)
#pragma unroll
      for (int r = 0; r < 4; ++r) {
        const size_t gm = (size_t)(m0 + wr * 64 + fi * 16 + r4 + r);
#pragma unroll
        for (int fj = 0; fj < 4; ++fj) {
          const int gn = n0 + wc * 64 + fj * 16 + cc;
          outBF[gm * (size_t)N + gn] = f2bf(acc[fi][fj][r]);
        }
      }
  } else {
    __shared__ ushortT tbuf[128 * 136];
#pragma unroll
    for (int fi = 0; fi < 4; ++fi)
#pragma unroll
      for (int r = 0; r < 4; ++r) {
        const int row = wr * 64 + fi * 16 + r4 + r;
        const size_t gm = (size_t)(m0 + row);
        float rs2 = 0.f, rs4 = 0.f;
#pragma unroll
        for (int fj = 0; fj < 4; ++fj) {
          const int col = wc * 64 + fj * 16 + cc;
          float sd = acc[fi][fj][r] + addend[gm * (size_t)N + n0 + col];
          tbuf[col * 136 + row] = f2bf(sd);
          float s2 = sd * sd;
          rs2 += s2;
          rs4 += s2 * s2;
        }
#pragma unroll
        for (int mk = 1; mk < 16; mk <<= 1) {
          rs2 += __shfl_xor(rs2, mk, 16);
          rs4 += __shfl_xor(rs4, mk, 16);
        }
        if (cc == 0) { atomicAdd(&S2[gm], rs2); atomicAdd(&S4[gm], rs4); }
      }
    __syncthreads();
#pragma unroll
    for (int i = 0; i < 8; ++i) {
      const int er = i * 16 + (tid >> 4);
      const int nc = (tid & 15) * 8;
      short8 v = *(const short8*)&tbuf[er * 136 + nc];
      *(short8*)&sdT[(size_t)(n0 + er) * (size_t)ldT + m0 + nc] = v;
    }
  }
}

// -------- 128x128 split-K GEMM for M = sdT sdT^T: partials, no scaling ------
__global__ __launch_bounds__(256) void mgemm128sk(
    const ushortT* __restrict__ T, int Dm, int K,
    float* __restrict__ pbuf)
{
  __shared__ ushortT sA[2][128 * 32];
  __shared__ ushortT sB[2][128 * 32];
  const int tid = threadIdx.x, w = tid >> 6, l = tid & 63;
  const int wr = w >> 1, wc = w & 1;
  const int i0 = blockIdx.x * 128, j0 = blockIdx.y * 128;
  const int kt0 = blockIdx.z * 64;
  f32x4 acc[4][4] = {};

  auto stage = [&](int buf, int kt) {
    const int k0 = kt << 5;
    const size_t col = (size_t)(k0 + (l & 3) * 8);
    const int rb = w * 16 + (l >> 2);
#pragma unroll
    for (int c = 0; c < 2; ++c) {
      gl_lds16(T + (size_t)(i0 + c * 64 + rb) * (size_t)K + col,
               &sA[buf][c * 2048 + w * 512]);
      gl_lds16(T + (size_t)(j0 + c * 64 + rb) * (size_t)K + col,
               &sB[buf][c * 2048 + w * 512]);
    }
  };

  stage(0, kt0);
  __syncthreads();

  for (int t = 0; t < 64; ++t) {
    const int buf = t & 1;
    if (t + 1 < 64) stage(buf ^ 1, kt0 + t + 1);
    const int ro = (l & 15) * 32 + (l >> 4) * 8;
    short8 a[4], b[4];
#pragma unroll
    for (int f = 0; f < 4; ++f) {
      a[f] = *(const short8*)&sA[buf][(wr * 64 + f * 16) * 32 + ro];
      b[f] = *(const short8*)&sB[buf][(wc * 64 + f * 16) * 32 + ro];
    }
#pragma unroll
    for (int fi = 0; fi < 4; ++fi)
#pragma unroll
      for (int fj = 0; fj < 4; ++fj)
        acc[fi][fj] = __builtin_amdgcn_mfma_f32_16x16x32_bf16(
            a[fi], b[fj], acc[fi][fj], 0, 0, 0);
    __syncthreads();
  }

  const int r4 = (l >> 4) * 4, cc = l & 15;
  float* out = pbuf + ((size_t)blockIdx.z << 20);
#pragma unroll
  for (int fi = 0; fi < 4; ++fi)
#pragma unroll
    for (int r = 0; r < 4; ++r) {
      const int gi = i0 + wr * 64 + fi * 16 + r4 + r;
#pragma unroll
      for (int fj = 0; fj < 4; ++fj) {
        const int gj = j0 + wc * 64 + fj * 16 + cc;
        out[(size_t)gi * (size_t)Dm + gj] = acc[fi][fj][r];
      }
    }
}

__global__ void reduce_grad(const float* __restrict__ pbuf,
                            float* __restrict__ grad, float invN) {
  const int i = blockIdx.x * 256 + threadIdx.x;
  const size_t base = (size_t)i * 4;
  f32x4 s = *(const f32x4*)(pbuf + base) + *(const f32x4*)(pbuf + base + (1u << 20)) +
            *(const f32x4*)(pbuf + base + (2u << 20)) + *(const f32x4*)(pbuf + base + (3u << 20));
  const int row = (int)(base >> 10), c0 = (int)(base & 1023);
  f32x4 o;
#pragma unroll
  for (int j = 0; j < 4; ++j)
    o[j] = 0.5f * (s[j] * invN) - ((row == c0 + j) ? 0.5f : 0.0f);
  *(f32x4*)(grad + base) = o;
}

// ------- merged prep: zero S2/S4 | cvt weight | transpose Q | make P --------
__global__ __launch_bounds__(256) void prep_misc(
    const float* __restrict__ weight, const float* __restrict__ decorr,
    ushortT* __restrict__ wbf, ushortT* __restrict__ qT,
    ushortT* __restrict__ pbf, float* __restrict__ S2S4)
{
  __shared__ float t[128][129];
  const int bid = blockIdx.x;
  const int tix = threadIdx.x;
  if (bid < 512) {  // weight f32 -> bf16 (524288 f32x4)
    const f32x4* in4 = (const f32x4*)weight;
    for (size_t i = (size_t)bid * 256 + tix; i < 524288; i += 512 * 256) {
      f32x4 v = in4[i];
      us4 o = { f2bf(v[0]), f2bf(v[1]), f2bf(v[2]), f2bf(v[3]) };
      *(us4*)(wbf + i * 4) = o;
    }
  } else if (bid < 1024) {  // make P = bf16(Q - I)
    const size_t base = ((size_t)(bid - 512) * 256 + tix) * 8;
    const int e = (int)(base >> 10);
    const int d0 = (int)(base & 1023);
    short8 v;
#pragma unroll
    for (int j = 0; j < 8; ++j) {
      float f = decorr[base + j] - ((e == d0 + j) ? 1.0f : 0.0f);
      v[j] = (short)f2bf(f);
    }
    *(short8*)(pbf + base) = v;
  } else if (bid < 1088) {  // transpose Q -> bf16 qT (64 tiles of 128^2)
    const int bi = (bid - 1024) & 7, bj = (bid - 1024) >> 3;
    const int tr = tix >> 5, tc = tix & 31;
#pragma unroll
    for (int i = 0; i < 16; ++i) {
      const int row = i * 8 + tr;
      f32x4 v = *(const f32x4*)&decorr[(size_t)(bi * 128 + row) * 1024 + bj * 128 + tc * 4];
#pragma unroll
      for (int j = 0; j < 4; ++j) t[row][tc * 4 + j] = v[j];
    }
    __syncthreads();
#pragma unroll
    for (int i = 0; i < 16; ++i) {
      const int dr = i * 8 + tr;
      us4 o = { f2bf(t[tc * 4 + 0][dr]), f2bf(t[tc * 4 + 1][dr]),
                f2bf(t[tc * 4 + 2][dr]), f2bf(t[tc * 4 + 3][dr]) };
      *(us4*)&qT[(size_t)(bj * 128 + dr) * 1024 + bi * 128 + tc * 4] = o;
    }
  } else {  // zero S2/S4 (16384 floats)
    S2S4[(bid - 1088) * 256 + tix] = 0.f;
  }
}

__global__ void gather_rows(const float* __restrict__ x, const int* __restrict__ idx,
                            float* __restrict__ self32, ushortT* __restrict__ selbf) {
  const int bid = blockIdx.x;
  const int b = bid >> 10;
  const int row = idx[bid] & 4095;
  const float4* src = (const float4*)(x + ((size_t)b * 4096 + (size_t)row) * 1024);
  const int t = threadIdx.x;
  float4 v = src[t];
  *(float4*)(self32 + (size_t)bid * 1024 + t * 4) = v;
  us4 o = { f2bf(v.x), f2bf(v.y), f2bf(v.z), f2bf(v.w) };
  *(us4*)(selbf + (size_t)bid * 1024 + t * 4) = o;
}

__global__ void loss_final(const float* __restrict__ S2, const float* __restrict__ S4,
                           float* __restrict__ out) {
  __shared__ double red0[256];
  __shared__ double red1[256];
  const int t = threadIdx.x;
  double ca = 0.0, wa = 0.0;
  for (int i = t; i < 8192; i += 256) {
    double s2 = (double)S2[i], s4 = (double)S4[i];
    ca += s2 * s2 - s4;
    wa += s4 - 2.0 * s2 + 1024.0;
  }
  red0[t] = ca; red1[t] = wa;
  __syncthreads();
  for (int s = 128; s > 0; s >>= 1) {
    if (t < s) { red0[t] += red0[t + s]; red1[t] += red1[t + s]; }
    __syncthreads();
  }
  if (t == 0) {
    const double inv = 1.0 / (8192.0 * 1024.0 * 1024.0);
    out[0] = (float)(red0[0] * inv);
    out[1] = (float)(red1[0] * inv);
  }
}

// ---------------- launch -----------------------------------------------------
extern "C" void kernel_launch(void* const* d_in, const int* in_sizes, int n_in,
                              void* d_out, int out_size, void* d_ws, size_t ws_size,
                              hipStream_t stream) {
  (void)in_sizes; (void)n_in; (void)out_size;
  const float* x = (const float*)d_in[0];
  const float* weight = (const float*)d_in[1];
  const float* bias = (const float*)d_in[2];
  const float* decorr = (const float*)d_in[3];
  const int* sidx = (const int*)d_in[4];

  if (ws_size < 146866176ULL) return;

  char* ws = (char*)d_ws;
  ushortT* fusedbf = (ushortT*)(ws + 67108864);
  ushortT* wbf     = (ushortT*)(ws + 71303168);
  ushortT* qT      = (ushortT*)(ws + 75497472);
  ushortT* pbf     = (ushortT*)(ws + 77594624);
  float*   self32  = (float*)  (ws + 79691776);
  ushortT* selbf   = (ushortT*)(ws + 113246208);
  ushortT* sdT     = (ushortT*)(ws + 130023424);
  float*   S2      = (float*)  (ws + 146800640);
  float*   S4      = (float*)  (ws + 146833408);

  float* y = (float*)d_out;
  float* grad = y + 67108864ULL;
  float* losses = grad + 1048576ULL;

  prep_misc<<<dim3(1152), dim3(256), 0, stream>>>(weight, decorr, wbf, qT, pbf, S2);
  gather_rows<<<dim3(8192), dim3(256), 0, stream>>>(x, sidx, self32, selbf);

  // fused = W @ Q  ->  bf16
  gemm128<1><<<dim3(16, 8), dim3(256), 0, stream>>>(
      wbf, qT, 2048, 1024, 1024, nullptr, fusedbf, nullptr, nullptr,
      nullptr, nullptr, nullptr, 0);
  // y = x(f32) @ fused^T + bias  — fused-convert reg-staged A, 2 blocks/CU
  gemmfx<<<dim3(2048), dim3(512), 0, stream>>>(x, fusedbf, y, bias);
  // sd = sel + sel @ P^T; S2/S4 row sums; sdT transposed bf16
  gemm128<2><<<dim3(64, 8), dim3(256), 0, stream>>>(
      selbf, pbf, 8192, 1024, 1024, nullptr, nullptr, nullptr, self32,
      S2, S4, sdT, 8192);
  // M partials = sdT sdT^T (split-K x4, 128^2 tiles), then reduce
  mgemm128sk<<<dim3(8, 8, 4), dim3(256), 0, stream>>>(sdT, 1024, 8192, self32);
  reduce_grad<<<dim3(1024), dim3(256), 0, stream>>>(self32, grad, 1.0f / 8192.0f);
  loss_final<<<dim3(1), dim3(256), 0, stream>>>(S2, S4, losses);
}

// Round 12
// 446.936 us; speedup vs baseline: 1.1022x; 1.1022x over previous
//
#include <hip/hip_runtime.h>
#include <hip/hip_bf16.h>
#include <cstdint>

typedef unsigned short ushortT;
typedef __attribute__((ext_vector_type(8))) short short8;
typedef __attribute__((ext_vector_type(4))) float f32x4;
typedef __attribute__((ext_vector_type(4))) unsigned short us4;

__device__ __forceinline__ ushortT f2bf(float f) {
  union { float f; unsigned u; } v; v.f = f;
  unsigned r = (v.u + 0x7FFFu + ((v.u >> 16) & 1u)) >> 16;
  return (ushortT)r;
}

__device__ __forceinline__ unsigned cvtpk(float lo, float hi) {
  unsigned r;
  asm("v_cvt_pk_bf16_f32 %0, %1, %2" : "=v"(r) : "v"(lo), "v"(hi));
  return r;
}

__device__ __forceinline__ void gl_lds16(const void* g, void* l) {
  __builtin_amdgcn_global_load_lds(
      (__attribute__((address_space(1))) void*)g,
      (__attribute__((address_space(3))) void*)l, 16, 0, 0);
}

// ===== fused f32->bf16 GEMM: y = x(f32) @ fused(bf16)^T + bias ==============
// r7 geometry: 256x128 tile, 8 waves (64x64/wave), mod-3 LDS (72 KiB),
// 2 blocks/CU (LDS-limited), one barrier per K-step, counted vmcnt. A is
// reg-staged from f32 x (v_cvt_pk_bf16_f32 -> 2 ds_write_b128), killing the
// separate cvt pass.
// NOTE launch_bounds (512,2): r11's (512,4) was read by hipcc as 4 blocks/CU
// -> 64-VGPR cap -> ~550 MB scratch spill (VGPR=64, WRITE_SIZE=822MB). This
// kernel needs ~112 VGPR; (512,2) caps at 128.
// Ledger (per iter kt): issue A(kt+2) 4 loads -> vmcnt(4) retires
// A(kt+1)x4+B(kt+1) -> ds_write A(kt+1) -> lgkmcnt(0) -> barrier ->
// issue B(kt+2) gl_lds -> ds_read + 16 MFMA from buf kt%3.
// Buffers mod 3: A-writes hit (kt+1)%3, B-DMA (kt+2)%3; readers on kt%3 ->
// disjoint in every barrier window. K=1024 hardcoded (NK=32).
__global__ __launch_bounds__(512, 2) void gemmfx(
    const float* __restrict__ X, const ushortT* __restrict__ B,
    float* __restrict__ outF, const float* __restrict__ bias)
{
  constexpr int NK = 32;
  constexpr int N = 2048;
  __shared__ ushortT smem[3 * 256 * 32 + 3 * 128 * 32];  // 72 KiB
  ushortT(*sA)[256 * 32] = (ushortT(*)[256 * 32])smem;
  ushortT(*sB)[128 * 32] = (ushortT(*)[128 * 32])(smem + 3 * 256 * 32);

  const int tid = threadIdx.x;
  const int wv = tid >> 6, l = tid & 63;
  const int wm = wv >> 1, wn = wv & 1;  // 4M x 2N waves, 64x64 each

  // XCD swizzle: n fast, m slow (per-XCD ws ~L2-resident, r8-verified)
  const int bid = blockIdx.x;
  const int xcd = bid & 7, ii = bid >> 3;
  const int n0 = (ii & 15) * 128;
  const int m0 = (xcd * 16 + (ii >> 4)) * 256;

  f32x4 acc[4][4] = {};

  // ---- A reg staging geometry: thread -> row ar, k-half ak (16 floats) ----
  const int ar = tid >> 1;
  const int ak = (tid & 1) * 16;
  const int aswz = (ar >> 1) & 3;
  const int ga0 = (tid & 1) * 2, ga1 = ga0 + 1;
  const float* Xrow = X + (size_t)(m0 + ar) * 1024 + ak;

  // ---- B staging (bf16 source, global_load_lds, r7 pattern) ----
  const ushortT* Bb = B + (size_t)n0 * 1024;
  const int rb = tid >> 2;
  const int gsb = (tid & 3) ^ ((rb >> 1) & 3);
  auto stageB = [&](int kt) {
    gl_lds16(Bb + (size_t)rb * 1024 + (size_t)((kt << 5) + (gsb << 3)),
             &sB[kt % 3][(wv * 16) * 32]);
  };

  auto writeA = [&](int kt, f32x4 (&wr)[4]) {
    ushortT* dst = &sA[kt % 3][ar * 32];
    union { unsigned u[4]; short8 s; } p0, p1;
    p0.u[0] = cvtpk(wr[0][0], wr[0][1]); p0.u[1] = cvtpk(wr[0][2], wr[0][3]);
    p0.u[2] = cvtpk(wr[1][0], wr[1][1]); p0.u[3] = cvtpk(wr[1][2], wr[1][3]);
    p1.u[0] = cvtpk(wr[2][0], wr[2][1]); p1.u[1] = cvtpk(wr[2][2], wr[2][3]);
    p1.u[2] = cvtpk(wr[3][0], wr[3][1]); p1.u[3] = cvtpk(wr[3][2], wr[3][3]);
    *(short8*)&dst[(ga0 ^ aswz) << 3] = p0.s;
    *(short8*)&dst[(ga1 ^ aswz) << 3] = p1.s;
  };

  const int fr = l & 15;
  const int colsw = (((l >> 4) ^ ((fr >> 1) & 3)) << 3);

  f32x4 ra0[4], ra1[4];

  // ---- prologue: A0->ra0, B0, A1->ra1, B1; retire A0+B0; write A0 ----
#pragma unroll
  for (int j = 0; j < 4; ++j) ra0[j] = *(const f32x4*)(Xrow + j * 4);
  stageB(0);
#pragma unroll
  for (int j = 0; j < 4; ++j) ra1[j] = *(const f32x4*)(Xrow + 32 + j * 4);
  stageB(1);
  asm volatile("s_waitcnt vmcnt(5)" ::: "memory");
  writeA(0, ra0);

  auto body = [&](int kt, f32x4 (&wr)[4], f32x4 (&ld)[4]) {
    if (kt + 2 < NK) {
#pragma unroll
      for (int j = 0; j < 4; ++j)
        ld[j] = *(const f32x4*)(Xrow + (kt + 2) * 32 + j * 4);
      asm volatile("s_waitcnt vmcnt(4)" ::: "memory");
    } else {
      asm volatile("s_waitcnt vmcnt(0)" ::: "memory");
    }
    if (kt + 1 < NK) writeA(kt + 1, wr);
    asm volatile("s_waitcnt lgkmcnt(0)" ::: "memory");
    __builtin_amdgcn_s_barrier();
    if (kt + 2 < NK) stageB(kt + 2);

    const ushortT* cA = sA[kt % 3];
    const ushortT* cB = sB[kt % 3];
    short8 av[4], bv[4];
#pragma unroll
    for (int f = 0; f < 4; ++f) {
      av[f] = *(const short8*)&cA[(wm * 64 + f * 16 + fr) * 32 + colsw];
      bv[f] = *(const short8*)&cB[(wn * 64 + f * 16 + fr) * 32 + colsw];
    }
    __builtin_amdgcn_s_setprio(1);
#pragma unroll
    for (int fi = 0; fi < 4; ++fi)
#pragma unroll
      for (int fj = 0; fj < 4; ++fj)
        acc[fi][fj] = __builtin_amdgcn_mfma_f32_16x16x32_bf16(
            av[fi], bv[fj], acc[fi][fj], 0, 0, 0);
    __builtin_amdgcn_s_setprio(0);
  };

#pragma unroll 1
  for (int kt2 = 0; kt2 < NK; kt2 += 2) {
    body(kt2, ra1, ra0);
    body(kt2 + 1, ra0, ra1);
  }

  // ---- epilogue: LDS transpose (padded) -> contiguous nt f32x4 stores ----
  const int cc = l & 15, r4 = (l >> 4) * 4;
  float bvv[4];
#pragma unroll
  for (int fj = 0; fj < 4; ++fj) bvv[fj] = bias[n0 + wn * 64 + fj * 16 + cc];

  float* lbuf = (float*)smem;  // 128 x 132 f32 = 67.6 KiB
#pragma unroll
  for (int s = 0; s < 2; ++s) {
    __syncthreads();
    if ((wm >> 1) == s) {
#pragma unroll
      for (int fi = 0; fi < 4; ++fi)
#pragma unroll
        for (int r = 0; r < 4; ++r) {
          const int row = (wm & 1) * 64 + fi * 16 + r4 + r;
#pragma unroll
          for (int fj = 0; fj < 4; ++fj)
            lbuf[row * 132 + wn * 64 + fj * 16 + cc] = acc[fi][fj][r] + bvv[fj];
        }
    }
    __syncthreads();
#pragma unroll
    for (int k = 0; k < 8; ++k) {
      const int f = k * 512 + tid;
      const int row = f >> 5, c4 = f & 31;
      f32x4 v = *(const f32x4*)&lbuf[row * 132 + c4 * 4];
      __builtin_nontemporal_store(
          v, (f32x4*)&outF[(size_t)(m0 + s * 128 + row) * (size_t)N + n0 + c4 * 4]);
    }
  }
}

// ---------------- 128x128 tile GEMM, C = A @ B^T, bf16 in, BK=32 -------------
template <int EPI>
__global__ __launch_bounds__(256) void gemm128(
    const ushortT* __restrict__ A, const ushortT* __restrict__ B,
    int M, int N, int K,
    float* __restrict__ outF, ushortT* __restrict__ outBF,
    const float* __restrict__ bias,
    const float* __restrict__ addend,
    float* __restrict__ S2, float* __restrict__ S4,
    ushortT* __restrict__ sdT, int ldT)
{
  __shared__ ushortT sA[2][128 * 32];
  __shared__ ushortT sB[2][128 * 32];
  const int tid = threadIdx.x;
  const int w = tid >> 6, l = tid & 63;
  const int wr = w >> 1, wc = w & 1;
  const int m0 = blockIdx.x * 128, n0 = blockIdx.y * 128;
  const int NK = K >> 5;

  f32x4 acc[4][4] = {};

  auto stage = [&](int buf, int kt) {
    const int k0 = kt << 5;
    const size_t colA = (size_t)(k0 + (l & 3) * 8);
    const int rb = w * 16 + (l >> 2);
#pragma unroll
    for (int c = 0; c < 2; ++c) {
      gl_lds16(A + (size_t)(m0 + c * 64 + rb) * (size_t)K + colA,
               &sA[buf][c * 2048 + w * 512]);
      gl_lds16(B + (size_t)(n0 + c * 64 + rb) * (size_t)K + colA,
               &sB[buf][c * 2048 + w * 512]);
    }
  };

  stage(0, 0);
  __syncthreads();

  for (int kt = 0; kt < NK; ++kt) {
    const int buf = kt & 1;
    if (kt + 1 < NK) stage(buf ^ 1, kt + 1);
    const int ro = (l & 15) * 32 + (l >> 4) * 8;
    short8 a[4], b[4];
#pragma unroll
    for (int f = 0; f < 4; ++f) {
      a[f] = *(const short8*)&sA[buf][(wr * 64 + f * 16) * 32 + ro];
      b[f] = *(const short8*)&sB[buf][(wc * 64 + f * 16) * 32 + ro];
    }
#pragma unroll
    for (int fi = 0; fi < 4; ++fi)
#pragma unroll
      for (int fj = 0; fj < 4; ++fj)
        acc[fi][fj] = __builtin_amdgcn_mfma_f32_16x16x32_bf16(
            a[fi], b[fj], acc[fi][fj], 0, 0, 0);
    __syncthreads();
  }

  const int r4 = (l >> 4) * 4, cc = l & 15;

  if constexpr (EPI == 1) {
#pragma unroll
    for (int fi = 0; fi < 4; ++fi)
#pragma unroll
      for (int r = 0; r < 4; ++r) {
        const size_t gm = (size_t)(m0 + wr * 64 + fi * 16 + r4 + r);
#pragma unroll
        for (int fj = 0; fj < 4; ++fj) {
          const int gn = n0 + wc * 64 + fj * 16 + cc;
          outBF[gm * (size_t)N + gn] = f2bf(acc[fi][fj][r]);
        }
      }
  } else {
    __shared__ ushortT tbuf[128 * 136];
#pragma unroll
    for (int fi = 0; fi < 4; ++fi)
#pragma unroll
      for (int r = 0; r < 4; ++r) {
        const int row = wr * 64 + fi * 16 + r4 + r;
        const size_t gm = (size_t)(m0 + row);
        float rs2 = 0.f, rs4 = 0.f;
#pragma unroll
        for (int fj = 0; fj < 4; ++fj) {
          const int col = wc * 64 + fj * 16 + cc;
          float sd = acc[fi][fj][r] + addend[gm * (size_t)N + n0 + col];
          tbuf[col * 136 + row] = f2bf(sd);
          float s2 = sd * sd;
          rs2 += s2;
          rs4 += s2 * s2;
        }
#pragma unroll
        for (int mk = 1; mk < 16; mk <<= 1) {
          rs2 += __shfl_xor(rs2, mk, 16);
          rs4 += __shfl_xor(rs4, mk, 16);
        }
        if (cc == 0) { atomicAdd(&S2[gm], rs2); atomicAdd(&S4[gm], rs4); }
      }
    __syncthreads();
#pragma unroll
    for (int i = 0; i < 8; ++i) {
      const int er = i * 16 + (tid >> 4);
      const int nc = (tid & 15) * 8;
      short8 v = *(const short8*)&tbuf[er * 136 + nc];
      *(short8*)&sdT[(size_t)(n0 + er) * (size_t)ldT + m0 + nc] = v;
    }
  }
}

// -------- 128x128 split-K GEMM for M = sdT sdT^T: partials, no scaling ------
__global__ __launch_bounds__(256) void mgemm128sk(
    const ushortT* __restrict__ T, int Dm, int K,
    float* __restrict__ pbuf)
{
  __shared__ ushortT sA[2][128 * 32];
  __shared__ ushortT sB[2][128 * 32];
  const int tid = threadIdx.x, w = tid >> 6, l = tid & 63;
  const int wr = w >> 1, wc = w & 1;
  const int i0 = blockIdx.x * 128, j0 = blockIdx.y * 128;
  const int kt0 = blockIdx.z * 64;
  f32x4 acc[4][4] = {};

  auto stage = [&](int buf, int kt) {
    const int k0 = kt << 5;
    const size_t col = (size_t)(k0 + (l & 3) * 8);
    const int rb = w * 16 + (l >> 2);
#pragma unroll
    for (int c = 0; c < 2; ++c) {
      gl_lds16(T + (size_t)(i0 + c * 64 + rb) * (size_t)K + col,
               &sA[buf][c * 2048 + w * 512]);
      gl_lds16(T + (size_t)(j0 + c * 64 + rb) * (size_t)K + col,
               &sB[buf][c * 2048 + w * 512]);
    }
  };

  stage(0, kt0);
  __syncthreads();

  for (int t = 0; t < 64; ++t) {
    const int buf = t & 1;
    if (t + 1 < 64) stage(buf ^ 1, kt0 + t + 1);
    const int ro = (l & 15) * 32 + (l >> 4) * 8;
    short8 a[4], b[4];
#pragma unroll
    for (int f = 0; f < 4; ++f) {
      a[f] = *(const short8*)&sA[buf][(wr * 64 + f * 16) * 32 + ro];
      b[f] = *(const short8*)&sB[buf][(wc * 64 + f * 16) * 32 + ro];
    }
#pragma unroll
    for (int fi = 0; fi < 4; ++fi)
#pragma unroll
      for (int fj = 0; fj < 4; ++fj)
        acc[fi][fj] = __builtin_amdgcn_mfma_f32_16x16x32_bf16(
            a[fi], b[fj], acc[fi][fj], 0, 0, 0);
    __syncthreads();
  }

  const int r4 = (l >> 4) * 4, cc = l & 15;
  float* out = pbuf + ((size_t)blockIdx.z << 20);
#pragma unroll
  for (int fi = 0; fi < 4; ++fi)
#pragma unroll
    for (int r = 0; r < 4; ++r) {
      const int gi = i0 + wr * 64 + fi * 16 + r4 + r;
#pragma unroll
      for (int fj = 0; fj < 4; ++fj) {
        const int gj = j0 + wc * 64 + fj * 16 + cc;
        out[(size_t)gi * (size_t)Dm + gj] = acc[fi][fj][r];
      }
    }
}

__global__ void reduce_grad(const float* __restrict__ pbuf,
                            float* __restrict__ grad, float invN) {
  const int i = blockIdx.x * 256 + threadIdx.x;
  const size_t base = (size_t)i * 4;
  f32x4 s = *(const f32x4*)(pbuf + base) + *(const f32x4*)(pbuf + base + (1u << 20)) +
            *(const f32x4*)(pbuf + base + (2u << 20)) + *(const f32x4*)(pbuf + base + (3u << 20));
  const int row = (int)(base >> 10), c0 = (int)(base & 1023);
  f32x4 o;
#pragma unroll
  for (int j = 0; j < 4; ++j)
    o[j] = 0.5f * (s[j] * invN) - ((row == c0 + j) ? 0.5f : 0.0f);
  *(f32x4*)(grad + base) = o;
}

// ------- merged prep: zero S2/S4 | cvt weight | transpose Q | make P --------
__global__ __launch_bounds__(256) void prep_misc(
    const float* __restrict__ weight, const float* __restrict__ decorr,
    ushortT* __restrict__ wbf, ushortT* __restrict__ qT,
    ushortT* __restrict__ pbf, float* __restrict__ S2S4)
{
  __shared__ float t[128][129];
  const int bid = blockIdx.x;
  const int tix = threadIdx.x;
  if (bid < 512) {  // weight f32 -> bf16 (524288 f32x4)
    const f32x4* in4 = (const f32x4*)weight;
    for (size_t i = (size_t)bid * 256 + tix; i < 524288; i += 512 * 256) {
      f32x4 v = in4[i];
      us4 o = { f2bf(v[0]), f2bf(v[1]), f2bf(v[2]), f2bf(v[3]) };
      *(us4*)(wbf + i * 4) = o;
    }
  } else if (bid < 1024) {  // make P = bf16(Q - I)
    const size_t base = ((size_t)(bid - 512) * 256 + tix) * 8;
    const int e = (int)(base >> 10);
    const int d0 = (int)(base & 1023);
    short8 v;
#pragma unroll
    for (int j = 0; j < 8; ++j) {
      float f = decorr[base + j] - ((e == d0 + j) ? 1.0f : 0.0f);
      v[j] = (short)f2bf(f);
    }
    *(short8*)(pbf + base) = v;
  } else if (bid < 1088) {  // transpose Q -> bf16 qT (64 tiles of 128^2)
    const int bi = (bid - 1024) & 7, bj = (bid - 1024) >> 3;
    const int tr = tix >> 5, tc = tix & 31;
#pragma unroll
    for (int i = 0; i < 16; ++i) {
      const int row = i * 8 + tr;
      f32x4 v = *(const f32x4*)&decorr[(size_t)(bi * 128 + row) * 1024 + bj * 128 + tc * 4];
#pragma unroll
      for (int j = 0; j < 4; ++j) t[row][tc * 4 + j] = v[j];
    }
    __syncthreads();
#pragma unroll
    for (int i = 0; i < 16; ++i) {
      const int dr = i * 8 + tr;
      us4 o = { f2bf(t[tc * 4 + 0][dr]), f2bf(t[tc * 4 + 1][dr]),
                f2bf(t[tc * 4 + 2][dr]), f2bf(t[tc * 4 + 3][dr]) };
      *(us4*)&qT[(size_t)(bj * 128 + dr) * 1024 + bi * 128 + tc * 4] = o;
    }
  } else {  // zero S2/S4 (16384 floats)
    S2S4[(bid - 1088) * 256 + tix] = 0.f;
  }
}

__global__ void gather_rows(const float* __restrict__ x, const int* __restrict__ idx,
                            float* __restrict__ self32, ushortT* __restrict__ selbf) {
  const int bid = blockIdx.x;
  const int b = bid >> 10;
  const int row = idx[bid] & 4095;
  const float4* src = (const float4*)(x + ((size_t)b * 4096 + (size_t)row) * 1024);
  const int t = threadIdx.x;
  float4 v = src[t];
  *(float4*)(self32 + (size_t)bid * 1024 + t * 4) = v;
  us4 o = { f2bf(v.x), f2bf(v.y), f2bf(v.z), f2bf(v.w) };
  *(us4*)(selbf + (size_t)bid * 1024 + t * 4) = o;
}

__global__ void loss_final(const float* __restrict__ S2, const float* __restrict__ S4,
                           float* __restrict__ out) {
  __shared__ double red0[256];
  __shared__ double red1[256];
  const int t = threadIdx.x;
  double ca = 0.0, wa = 0.0;
  for (int i = t; i < 8192; i += 256) {
    double s2 = (double)S2[i], s4 = (double)S4[i];
    ca += s2 * s2 - s4;
    wa += s4 - 2.0 * s2 + 1024.0;
  }
  red0[t] = ca; red1[t] = wa;
  __syncthreads();
  for (int s = 128; s > 0; s >>= 1) {
    if (t < s) { red0[t] += red0[t + s]; red1[t] += red1[t + s]; }
    __syncthreads();
  }
  if (t == 0) {
    const double inv = 1.0 / (8192.0 * 1024.0 * 1024.0);
    out[0] = (float)(red0[0] * inv);
    out[1] = (float)(red1[0] * inv);
  }
}

// ---------------- launch -----------------------------------------------------
extern "C" void kernel_launch(void* const* d_in, const int* in_sizes, int n_in,
                              void* d_out, int out_size, void* d_ws, size_t ws_size,
                              hipStream_t stream) {
  (void)in_sizes; (void)n_in; (void)out_size;
  const float* x = (const float*)d_in[0];
  const float* weight = (const float*)d_in[1];
  const float* bias = (const float*)d_in[2];
  const float* decorr = (const float*)d_in[3];
  const int* sidx = (const int*)d_in[4];

  if (ws_size < 146866176ULL) return;

  char* ws = (char*)d_ws;
  ushortT* fusedbf = (ushortT*)(ws + 67108864);
  ushortT* wbf     = (ushortT*)(ws + 71303168);
  ushortT* qT      = (ushortT*)(ws + 75497472);
  ushortT* pbf     = (ushortT*)(ws + 77594624);
  float*   self32  = (float*)  (ws + 79691776);
  ushortT* selbf   = (ushortT*)(ws + 113246208);
  ushortT* sdT     = (ushortT*)(ws + 130023424);
  float*   S2      = (float*)  (ws + 146800640);
  float*   S4      = (float*)  (ws + 146833408);

  float* y = (float*)d_out;
  float* grad = y + 67108864ULL;
  float* losses = grad + 1048576ULL;

  prep_misc<<<dim3(1152), dim3(256), 0, stream>>>(weight, decorr, wbf, qT, pbf, S2);
  gather_rows<<<dim3(8192), dim3(256), 0, stream>>>(x, sidx, self32, selbf);

  // fused = W @ Q  ->  bf16
  gemm128<1><<<dim3(16, 8), dim3(256), 0, stream>>>(
      wbf, qT, 2048, 1024, 1024, nullptr, fusedbf, nullptr, nullptr,
      nullptr, nullptr, nullptr, 0);
  // y = x(f32) @ fused^T + bias  — fused-convert reg-staged A, 2 blocks/CU
  gemmfx<<<dim3(2048), dim3(512), 0, stream>>>(x, fusedbf, y, bias);
  // sd = sel + sel @ P^T; S2/S4 row sums; sdT transposed bf16
  gemm128<2><<<dim3(64, 8), dim3(256), 0, stream>>>(
      selbf, pbf, 8192, 1024, 1024, nullptr, nullptr, nullptr, self32,
      S2, S4, sdT, 8192);
  // M partials = sdT sdT^T (split-K x4, 128^2 tiles), then reduce
  mgemm128sk<<<dim3(8, 8, 4), dim3(256), 0, stream>>>(sdT, 1024, 8192, self32);
  reduce_grad<<<dim3(1024), dim3(256), 0, stream>>>(self32, grad, 1.0f / 8192.0f);
  loss_final<<<dim3(1), dim3(256), 0, stream>>>(S2, S4, losses);
}

// Round 13
// 307.979 us; speedup vs baseline: 1.5995x; 1.4512x over previous
//
#include <hip/hip_runtime.h>
#include <hip/hip_bf16.h>
#include <cstdint>

typedef unsigned short ushortT;
typedef __attribute__((ext_vector_type(8))) short short8;
typedef __attribute__((ext_vector_type(4))) float f32x4;
typedef __attribute__((ext_vector_type(4))) unsigned short us4;

__device__ __forceinline__ ushortT f2bf(float f) {
  union { float f; unsigned u; } v; v.f = f;
  unsigned r = (v.u + 0x7FFFu + ((v.u >> 16) & 1u)) >> 16;
  return (ushortT)r;
}

__device__ __forceinline__ void gl_lds16(const void* g, void* l) {
  __builtin_amdgcn_global_load_lds(
      (__attribute__((address_space(1))) void*)g,
      (__attribute__((address_space(3))) void*)l, 16, 0, 0);
}

// ============ 256x128 tile, 8-wave, 2 blocks/CU, counted-vmcnt GEMM ==========
// (r8 kernel, proven: 160us, 60 VGPR, MfmaUtil 35%, FETCH 139MB, 0 conflicts)
// C = A @ B^T + bias. BK=32, 3 LDS buffers (72 KiB) -> 2 blocks/CU (TLP).
// XCD swizzle: n fast, m slow -> per-XCD ws = 4 m-panels + 16 n-panels ~ L2.
// NOTE: hipcc __launch_bounds__ arg2 acts as a blocks/CU-style VGPR cap
// (r11/r12 evidence: arg=4 -> 64-VGPR cap, arg=2 -> ~128). This kernel needs
// only 60 VGPR, so (512,4) is safe AND enforces the cap that keeps 2 blk/CU.
__global__ __launch_bounds__(512, 4) void gemm256(
    const ushortT* __restrict__ A, const ushortT* __restrict__ B,
    int M, int N, int K,
    float* __restrict__ outF, const float* __restrict__ bias)
{
  __shared__ ushortT smem[3 * 256 * 32 + 3 * 128 * 32];  // 72 KiB
  ushortT(*sA)[256 * 32] = (ushortT(*)[256 * 32])smem;
  ushortT(*sB)[128 * 32] = (ushortT(*)[128 * 32])(smem + 3 * 256 * 32);

  const int tid = threadIdx.x;
  const int wv = tid >> 6, l = tid & 63;
  const int wm = wv >> 1, wn = wv & 1;  // 4M x 2N waves, 64x64 each

  const int bid = blockIdx.x;
  const int xcd = bid & 7, i = bid >> 3;
  const int n0 = (i & 15) * 128;                // 16 n-panels (fast)
  const int m0 = (xcd * 16 + (i >> 4)) * 256;   // 128 m-panels (slow)
  const int NK = K >> 5;

  f32x4 acc[4][4] = {};

  const ushortT* Ab = A + (size_t)m0 * (size_t)K;
  const ushortT* Bb = B + (size_t)n0 * (size_t)K;

  const int sr = tid >> 2;
  const int sg = tid & 3;
  const int gsw = sg ^ ((sr >> 1) & 3);

  auto stage = [&](int kt) {
    const int b = kt % 3;
    const size_t kof = (size_t)((kt << 5) + (gsw << 3));
    gl_lds16(Ab + (size_t)sr * (size_t)K + kof,         &sA[b][(wv * 16) * 32]);
    gl_lds16(Ab + (size_t)(128 + sr) * (size_t)K + kof, &sA[b][(128 + wv * 16) * 32]);
    gl_lds16(Bb + (size_t)sr * (size_t)K + kof,         &sB[b][(wv * 16) * 32]);
  };

  const int fr = l & 15;
  const int colsw = (((l >> 4) ^ ((fr >> 1) & 3)) << 3);

  stage(0);
  stage(1);

  for (int kt = 0; kt < NK; ++kt) {
    if (kt + 1 < NK) asm volatile("s_waitcnt vmcnt(3)" ::: "memory");
    else             asm volatile("s_waitcnt vmcnt(0)" ::: "memory");
    __builtin_amdgcn_s_barrier();
    if (kt + 2 < NK) stage(kt + 2);

    const int bc = kt % 3;
    short8 av[4], bv8[4];
#pragma unroll
    for (int fi = 0; fi < 4; ++fi)
      av[fi] = *(const short8*)&sA[bc][(wm * 64 + fi * 16 + fr) * 32 + colsw];
#pragma unroll
    for (int fj = 0; fj < 4; ++fj)
      bv8[fj] = *(const short8*)&sB[bc][(wn * 64 + fj * 16 + fr) * 32 + colsw];

    __builtin_amdgcn_s_setprio(1);
#pragma unroll
    for (int fi = 0; fi < 4; ++fi)
#pragma unroll
      for (int fj = 0; fj < 4; ++fj)
        acc[fi][fj] = __builtin_amdgcn_mfma_f32_16x16x32_bf16(
            av[fi], bv8[fj], acc[fi][fj], 0, 0, 0);
    __builtin_amdgcn_s_setprio(0);
  }

  // ---- epilogue: LDS transpose (padded stride) -> contiguous nt stores ----
  const int cc = l & 15, r4 = (l >> 4) * 4;
  float bvv[4];
#pragma unroll
  for (int fj = 0; fj < 4; ++fj) bvv[fj] = bias[n0 + wn * 64 + fj * 16 + cc];

  float* lbuf = (float*)smem;  // 128 rows x 132 stride f32 = 67.6 KiB
#pragma unroll
  for (int s = 0; s < 2; ++s) {
    __syncthreads();
    if ((wm >> 1) == s) {
#pragma unroll
      for (int fi = 0; fi < 4; ++fi)
#pragma unroll
        for (int r = 0; r < 4; ++r) {
          const int row = (wm & 1) * 64 + fi * 16 + r4 + r;
#pragma unroll
          for (int fj = 0; fj < 4; ++fj)
            lbuf[row * 132 + wn * 64 + fj * 16 + cc] = acc[fi][fj][r] + bvv[fj];
        }
    }
    __syncthreads();
#pragma unroll
    for (int k = 0; k < 8; ++k) {
      const int f = k * 512 + tid;
      const int row = f >> 5, c4 = f & 31;
      f32x4 v = *(const f32x4*)&lbuf[row * 132 + c4 * 4];
      __builtin_nontemporal_store(
          v, (f32x4*)&outF[(size_t)(m0 + s * 128 + row) * (size_t)N + n0 + c4 * 4]);
    }
  }
}

// ---------------- 128x128 tile GEMM, C = A @ B^T, bf16 in, BK=32 -------------
template <int EPI>
__global__ __launch_bounds__(256) void gemm128(
    const ushortT* __restrict__ A, const ushortT* __restrict__ B,
    int M, int N, int K,
    float* __restrict__ outF, ushortT* __restrict__ outBF,
    const float* __restrict__ bias,
    const float* __restrict__ addend,
    float* __restrict__ S2, float* __restrict__ S4,
    ushortT* __restrict__ sdT, int ldT)
{
  __shared__ ushortT sA[2][128 * 32];
  __shared__ ushortT sB[2][128 * 32];
  const int tid = threadIdx.x;
  const int w = tid >> 6, l = tid & 63;
  const int wr = w >> 1, wc = w & 1;
  const int m0 = blockIdx.x * 128, n0 = blockIdx.y * 128;
  const int NK = K >> 5;

  f32x4 acc[4][4] = {};

  auto stage = [&](int buf, int kt) {
    const int k0 = kt << 5;
    const size_t colA = (size_t)(k0 + (l & 3) * 8);
    const int rb = w * 16 + (l >> 2);
#pragma unroll
    for (int c = 0; c < 2; ++c) {
      gl_lds16(A + (size_t)(m0 + c * 64 + rb) * (size_t)K + colA,
               &sA[buf][c * 2048 + w * 512]);
      gl_lds16(B + (size_t)(n0 + c * 64 + rb) * (size_t)K + colA,
               &sB[buf][c * 2048 + w * 512]);
    }
  };

  stage(0, 0);
  __syncthreads();

  for (int kt = 0; kt < NK; ++kt) {
    const int buf = kt & 1;
    if (kt + 1 < NK) stage(buf ^ 1, kt + 1);
    const int ro = (l & 15) * 32 + (l >> 4) * 8;
    short8 a[4], b[4];
#pragma unroll
    for (int f = 0; f < 4; ++f) {
      a[f] = *(const short8*)&sA[buf][(wr * 64 + f * 16) * 32 + ro];
      b[f] = *(const short8*)&sB[buf][(wc * 64 + f * 16) * 32 + ro];
    }
#pragma unroll
    for (int fi = 0; fi < 4; ++fi)
#pragma unroll
      for (int fj = 0; fj < 4; ++fj)
        acc[fi][fj] = __builtin_amdgcn_mfma_f32_16x16x32_bf16(
            a[fi], b[fj], acc[fi][fj], 0, 0, 0);
    __syncthreads();
  }

  const int r4 = (l >> 4) * 4, cc = l & 15;

  if constexpr (EPI == 1) {
#pragma unroll
    for (int fi = 0; fi < 4; ++fi)
#pragma unroll
      for (int r = 0; r < 4; ++r) {
        const size_t gm = (size_t)(m0 + wr * 64 + fi * 16 + r4 + r);
#pragma unroll
        for (int fj = 0; fj < 4; ++fj) {
          const int gn = n0 + wc * 64 + fj * 16 + cc;
          outBF[gm * (size_t)N + gn] = f2bf(acc[fi][fj][r]);
        }
      }
  } else {
    __shared__ ushortT tbuf[128 * 136];
#pragma unroll
    for (int fi = 0; fi < 4; ++fi)
#pragma unroll
      for (int r = 0; r < 4; ++r) {
        const int row = wr * 64 + fi * 16 + r4 + r;
        const size_t gm = (size_t)(m0 + row);
        float rs2 = 0.f, rs4 = 0.f;
#pragma unroll
        for (int fj = 0; fj < 4; ++fj) {
          const int col = wc * 64 + fj * 16 + cc;
          float sd = acc[fi][fj][r] + addend[gm * (size_t)N + n0 + col];
          tbuf[col * 136 + row] = f2bf(sd);
          float s2 = sd * sd;
          rs2 += s2;
          rs4 += s2 * s2;
        }
#pragma unroll
        for (int mk = 1; mk < 16; mk <<= 1) {
          rs2 += __shfl_xor(rs2, mk, 16);
          rs4 += __shfl_xor(rs4, mk, 16);
        }
        if (cc == 0) { atomicAdd(&S2[gm], rs2); atomicAdd(&S4[gm], rs4); }
      }
    __syncthreads();
#pragma unroll
    for (int i = 0; i < 8; ++i) {
      const int er = i * 16 + (tid >> 4);
      const int nc = (tid & 15) * 8;
      short8 v = *(const short8*)&tbuf[er * 136 + nc];
      *(short8*)&sdT[(size_t)(n0 + er) * (size_t)ldT + m0 + nc] = v;
    }
  }
}

// -------- 128x128 split-K GEMM for M = sdT sdT^T: partials, no scaling ------
__global__ __launch_bounds__(256) void mgemm128sk(
    const ushortT* __restrict__ T, int Dm, int K,
    float* __restrict__ pbuf)
{
  __shared__ ushortT sA[2][128 * 32];
  __shared__ ushortT sB[2][128 * 32];
  const int tid = threadIdx.x, w = tid >> 6, l = tid & 63;
  const int wr = w >> 1, wc = w & 1;
  const int i0 = blockIdx.x * 128, j0 = blockIdx.y * 128;
  const int kt0 = blockIdx.z * 64;
  f32x4 acc[4][4] = {};

  auto stage = [&](int buf, int kt) {
    const int k0 = kt << 5;
    const size_t col = (size_t)(k0 + (l & 3) * 8);
    const int rb = w * 16 + (l >> 2);
#pragma unroll
    for (int c = 0; c < 2; ++c) {
      gl_lds16(T + (size_t)(i0 + c * 64 + rb) * (size_t)K + col,
               &sA[buf][c * 2048 + w * 512]);
      gl_lds16(T + (size_t)(j0 + c * 64 + rb) * (size_t)K + col,
               &sB[buf][c * 2048 + w * 512]);
    }
  };

  stage(0, kt0);
  __syncthreads();

  for (int t = 0; t < 64; ++t) {
    const int buf = t & 1;
    if (t + 1 < 64) stage(buf ^ 1, kt0 + t + 1);
    const int ro = (l & 15) * 32 + (l >> 4) * 8;
    short8 a[4], b[4];
#pragma unroll
    for (int f = 0; f < 4; ++f) {
      a[f] = *(const short8*)&sA[buf][(wr * 64 + f * 16) * 32 + ro];
      b[f] = *(const short8*)&sB[buf][(wc * 64 + f * 16) * 32 + ro];
    }
#pragma unroll
    for (int fi = 0; fi < 4; ++fi)
#pragma unroll
      for (int fj = 0; fj < 4; ++fj)
        acc[fi][fj] = __builtin_amdgcn_mfma_f32_16x16x32_bf16(
            a[fi], b[fj], acc[fi][fj], 0, 0, 0);
    __syncthreads();
  }

  const int r4 = (l >> 4) * 4, cc = l & 15;
  float* out = pbuf + ((size_t)blockIdx.z << 20);
#pragma unroll
  for (int fi = 0; fi < 4; ++fi)
#pragma unroll
    for (int r = 0; r < 4; ++r) {
      const int gi = i0 + wr * 64 + fi * 16 + r4 + r;
#pragma unroll
      for (int fj = 0; fj < 4; ++fj) {
        const int gj = j0 + wc * 64 + fj * 16 + cc;
        out[(size_t)gi * (size_t)Dm + gj] = acc[fi][fj][r];
      }
    }
}

__global__ void reduce_grad(const float* __restrict__ pbuf,
                            float* __restrict__ grad, float invN) {
  const int i = blockIdx.x * 256 + threadIdx.x;
  const size_t base = (size_t)i * 4;
  f32x4 s = *(const f32x4*)(pbuf + base) + *(const f32x4*)(pbuf + base + (1u << 20)) +
            *(const f32x4*)(pbuf + base + (2u << 20)) + *(const f32x4*)(pbuf + base + (3u << 20));
  const int row = (int)(base >> 10), c0 = (int)(base & 1023);
  f32x4 o;
#pragma unroll
  for (int j = 0; j < 4; ++j)
    o[j] = 0.5f * (s[j] * invN) - ((row == c0 + j) ? 0.5f : 0.0f);
  *(f32x4*)(grad + base) = o;
}

// ==== merged prep+gather: cvt x | cvt w | make P | transpose Q | zero | gather
// Block ranges (all branches block-uniform; LDS 16.9 KB max):
//  [0,2048)      cvt x f32->bf16 (nt loads, grid-stride 16/thread)
//  [2048,2560)   cvt weight
//  [2560,3072)   make P = bf16(Q - I)
//  [3072,3328)   transpose Q -> bf16 qT (64x64 tiles)
//  [3328,3392)   zero S2/S4
//  [3392,11584)  gather rows -> self32 + selbf
__global__ __launch_bounds__(256) void prep_all(
    const float* __restrict__ x, const float* __restrict__ weight,
    const float* __restrict__ decorr, const int* __restrict__ idx,
    ushortT* __restrict__ xbf, ushortT* __restrict__ wbf,
    ushortT* __restrict__ qT, ushortT* __restrict__ pbf,
    float* __restrict__ S2S4,
    float* __restrict__ self32, ushortT* __restrict__ selbf)
{
  __shared__ float t[64][65];
  const int bid = blockIdx.x;
  const int tix = threadIdx.x;
  if (bid < 2048) {
    const f32x4* in4 = (const f32x4*)x;
    for (size_t i = (size_t)bid * 256 + tix; i < 8388608ULL; i += 2048ULL * 256) {
      f32x4 v = __builtin_nontemporal_load(&in4[i]);
      us4 o = { f2bf(v[0]), f2bf(v[1]), f2bf(v[2]), f2bf(v[3]) };
      *(us4*)(xbf + i * 4) = o;
    }
  } else if (bid < 2560) {
    const f32x4* in4 = (const f32x4*)weight;
    for (size_t i = (size_t)(bid - 2048) * 256 + tix; i < 524288ULL; i += 512ULL * 256) {
      f32x4 v = in4[i];
      us4 o = { f2bf(v[0]), f2bf(v[1]), f2bf(v[2]), f2bf(v[3]) };
      *(us4*)(wbf + i * 4) = o;
    }
  } else if (bid < 3072) {
    const size_t base = ((size_t)(bid - 2560) * 256 + tix) * 8;
    const int e = (int)(base >> 10);
    const int d0 = (int)(base & 1023);
    short8 v;
#pragma unroll
    for (int j = 0; j < 8; ++j) {
      float f = decorr[base + j] - ((e == d0 + j) ? 1.0f : 0.0f);
      v[j] = (short)f2bf(f);
    }
    *(short8*)(pbf + base) = v;
  } else if (bid < 3328) {
    const int tq = bid - 3072;
    const int bi = tq & 15, bj = tq >> 4;  // k-tile, d-tile
    const int tr = tix >> 4, tc = tix & 15;
#pragma unroll
    for (int i = 0; i < 4; ++i) {
      const int row = i * 16 + tr;
      f32x4 v = *(const f32x4*)&decorr[(size_t)(bi * 64 + row) * 1024 + bj * 64 + tc * 4];
#pragma unroll
      for (int j = 0; j < 4; ++j) t[row][tc * 4 + j] = v[j];
    }
    __syncthreads();
#pragma unroll
    for (int i = 0; i < 4; ++i) {
      const int dr = i * 16 + tr;
      us4 o = { f2bf(t[tc * 4 + 0][dr]), f2bf(t[tc * 4 + 1][dr]),
                f2bf(t[tc * 4 + 2][dr]), f2bf(t[tc * 4 + 3][dr]) };
      *(us4*)&qT[(size_t)(bj * 64 + dr) * 1024 + bi * 64 + tc * 4] = o;
    }
  } else if (bid < 3392) {
    S2S4[(bid - 3328) * 256 + tix] = 0.f;
  } else {
    const int g = bid - 3392;                 // 0..8191
    const int b = g >> 10;
    const int row = idx[g] & 4095;
    const f32x4* src = (const f32x4*)(x + ((size_t)b * 4096 + (size_t)row) * 1024);
    f32x4 v = src[tix];
    *(f32x4*)(self32 + (size_t)g * 1024 + tix * 4) = v;
    us4 o = { f2bf(v[0]), f2bf(v[1]), f2bf(v[2]), f2bf(v[3]) };
    *(us4*)(selbf + (size_t)g * 1024 + tix * 4) = o;
  }
}

__global__ void loss_final(const float* __restrict__ S2, const float* __restrict__ S4,
                           float* __restrict__ out) {
  __shared__ double red0[256];
  __shared__ double red1[256];
  const int t = threadIdx.x;
  double ca = 0.0, wa = 0.0;
  for (int i = t; i < 8192; i += 256) {
    double s2 = (double)S2[i], s4 = (double)S4[i];
    ca += s2 * s2 - s4;
    wa += s4 - 2.0 * s2 + 1024.0;
  }
  red0[t] = ca; red1[t] = wa;
  __syncthreads();
  for (int s = 128; s > 0; s >>= 1) {
    if (t < s) { red0[t] += red0[t + s]; red1[t] += red1[t + s]; }
    __syncthreads();
  }
  if (t == 0) {
    const double inv = 1.0 / (8192.0 * 1024.0 * 1024.0);
    out[0] = (float)(red0[0] * inv);
    out[1] = (float)(red1[0] * inv);
  }
}

// ---------------- launch -----------------------------------------------------
extern "C" void kernel_launch(void* const* d_in, const int* in_sizes, int n_in,
                              void* d_out, int out_size, void* d_ws, size_t ws_size,
                              hipStream_t stream) {
  (void)in_sizes; (void)n_in; (void)out_size;
  const float* x = (const float*)d_in[0];
  const float* weight = (const float*)d_in[1];
  const float* bias = (const float*)d_in[2];
  const float* decorr = (const float*)d_in[3];
  const int* sidx = (const int*)d_in[4];

  if (ws_size < 146866176ULL) return;

  char* ws = (char*)d_ws;
  ushortT* xbf     = (ushortT*)(ws);
  ushortT* fusedbf = (ushortT*)(ws + 67108864);
  ushortT* wbf     = (ushortT*)(ws + 71303168);
  ushortT* qT      = (ushortT*)(ws + 75497472);
  ushortT* pbf     = (ushortT*)(ws + 77594624);
  float*   self32  = (float*)  (ws + 79691776);
  ushortT* selbf   = (ushortT*)(ws + 113246208);
  ushortT* sdT     = (ushortT*)(ws + 130023424);
  float*   S2      = (float*)  (ws + 146800640);
  float*   S4      = (float*)  (ws + 146833408);

  float* y = (float*)d_out;
  float* grad = y + 67108864ULL;
  float* losses = grad + 1048576ULL;

  // all prep + gather in one dispatch
  prep_all<<<dim3(11584), dim3(256), 0, stream>>>(
      x, weight, decorr, sidx, xbf, wbf, qT, pbf, S2, self32, selbf);

  // fused = W @ Q  ->  bf16
  gemm128<1><<<dim3(16, 8), dim3(256), 0, stream>>>(
      wbf, qT, 2048, 1024, 1024, nullptr, fusedbf, nullptr, nullptr,
      nullptr, nullptr, nullptr, 0);
  // y = x @ fused^T + bias  — r8 gemm256 (proven 160us)
  gemm256<<<dim3(2048), dim3(512), 0, stream>>>(
      xbf, fusedbf, 32768, 2048, 1024, y, bias);
  // sd = sel + sel @ P^T; S2/S4 row sums; sdT transposed bf16
  gemm128<2><<<dim3(64, 8), dim3(256), 0, stream>>>(
      selbf, pbf, 8192, 1024, 1024, nullptr, nullptr, nullptr, self32,
      S2, S4, sdT, 8192);
  // M partials = sdT sdT^T (split-K x4, 128^2 tiles), then reduce
  mgemm128sk<<<dim3(8, 8, 4), dim3(256), 0, stream>>>(sdT, 1024, 8192, self32);
  reduce_grad<<<dim3(1024), dim3(256), 0, stream>>>(self32, grad, 1.0f / 8192.0f);
  loss_final<<<dim3(1), dim3(256), 0, stream>>>(S2, S4, losses);
}